// Round 1
// baseline (390.694 us; speedup 1.0000x reference)
//
#include <hip/hip_runtime.h>

// Problem: r = 1 - 0.5*(var(x+y) - var(x) - var(y)) / sqrt(|var(x)*var(y)|),
// per row of 65536 elements (768 rows), then mean over rows.
// Identity: 0.5*(var(x+y)-var(x)-var(y)) == cov(x,y) (ddof=1), so five
// sufficient statistics per row suffice: Sx, Sy, Sxx, Syy, Sxy.

#define ROWS 768          // 8*16*6
#define ROW_ELEMS 65536   // 256*256
#define BLOCK 256

__global__ __launch_bounds__(BLOCK) void row_r_kernel(const float* __restrict__ x,
                                                      const float* __restrict__ y,
                                                      float* __restrict__ row_r) {
    const int row = blockIdx.x;
    const float4* __restrict__ x4 = (const float4*)(x + (size_t)row * ROW_ELEMS);
    const float4* __restrict__ y4 = (const float4*)(y + (size_t)row * ROW_ELEMS);
    const int tid = threadIdx.x;

    float sx = 0.f, sy = 0.f, sxx = 0.f, syy = 0.f, sxy = 0.f;

    const int nvec = ROW_ELEMS / 4;  // 16384 float4s per row
    for (int i = tid; i < nvec; i += BLOCK) {
        float4 a = x4[i];
        float4 b = y4[i];
        sx  += a.x + a.y + a.z + a.w;
        sy  += b.x + b.y + b.z + b.w;
        sxx += a.x*a.x + a.y*a.y + a.z*a.z + a.w*a.w;
        syy += b.x*b.x + b.y*b.y + b.z*b.z + b.w*b.w;
        sxy += a.x*b.x + a.y*b.y + a.z*b.z + a.w*b.w;
    }

    // wave (64-lane) shuffle reduction
    #pragma unroll
    for (int off = 32; off > 0; off >>= 1) {
        sx  += __shfl_down(sx,  off);
        sy  += __shfl_down(sy,  off);
        sxx += __shfl_down(sxx, off);
        syy += __shfl_down(syy, off);
        sxy += __shfl_down(sxy, off);
    }

    __shared__ float sm[5][BLOCK / 64];
    const int wave = tid >> 6;
    const int lane = tid & 63;
    if (lane == 0) {
        sm[0][wave] = sx;  sm[1][wave] = sy;
        sm[2][wave] = sxx; sm[3][wave] = syy;
        sm[4][wave] = sxy;
    }
    __syncthreads();

    if (tid == 0) {
        float tsx = 0.f, tsy = 0.f, tsxx = 0.f, tsyy = 0.f, tsxy = 0.f;
        #pragma unroll
        for (int w = 0; w < BLOCK / 64; ++w) {
            tsx += sm[0][w]; tsy += sm[1][w];
            tsxx += sm[2][w]; tsyy += sm[3][w];
            tsxy += sm[4][w];
        }
        const float n = (float)ROW_ELEMS;
        const float inv_nm1 = 1.0f / (n - 1.0f);
        float vx  = (tsxx - tsx * tsx / n) * inv_nm1;
        float vy  = (tsyy - tsy * tsy / n) * inv_nm1;
        float cov = (tsxy - tsx * tsy / n) * inv_nm1;  // == 0.5*(vxy - vx - vy)
        float r = 1.0f - cov / sqrtf(fabsf(vx * vy));
        row_r[row] = r;
    }
}

__global__ __launch_bounds__(BLOCK) void mean_kernel(const float* __restrict__ row_r,
                                                     float* __restrict__ out) {
    float s = 0.f;
    for (int i = threadIdx.x; i < ROWS; i += BLOCK) s += row_r[i];

    #pragma unroll
    for (int off = 32; off > 0; off >>= 1) s += __shfl_down(s, off);

    __shared__ float sm[BLOCK / 64];
    const int wave = threadIdx.x >> 6;
    const int lane = threadIdx.x & 63;
    if (lane == 0) sm[wave] = s;
    __syncthreads();

    if (threadIdx.x == 0) {
        float t = 0.f;
        #pragma unroll
        for (int w = 0; w < BLOCK / 64; ++w) t += sm[w];
        out[0] = t / (float)ROWS;
    }
}

extern "C" void kernel_launch(void* const* d_in, const int* in_sizes, int n_in,
                              void* d_out, int out_size, void* d_ws, size_t ws_size,
                              hipStream_t stream) {
    const float* x = (const float*)d_in[0];
    const float* y = (const float*)d_in[1];
    float* row_r = (float*)d_ws;          // 768 floats of scratch
    float* out = (float*)d_out;

    row_r_kernel<<<ROWS, BLOCK, 0, stream>>>(x, y, row_r);
    mean_kernel<<<1, BLOCK, 0, stream>>>(row_r, out);
}

// Round 2
// 388.560 us; speedup vs baseline: 1.0055x; 1.0055x over previous
//
#include <hip/hip_runtime.h>

// r = 1 - cov(x,y)/sqrt(|var(x)*var(y)|) per row (cov identity for
// 0.5*(var(x+y)-var(x)-var(y))), then mean over 768 rows.
// Pass 1: 5 sufficient stats (Sx,Sy,Sxx,Syy,Sxy) per (row,chunk) block.
// Pass 2: single block combines chunks -> per-row r -> mean.

#define ROWS 768          // 8*16*6
#define ROW_ELEMS 65536   // 256*256
#define BLOCK 256
#define SPLIT 4                         // chunks per row
#define NBLK (ROWS * SPLIT)             // 3072 partial blocks
#define CHUNK_VECS (ROW_ELEMS / 4 / SPLIT)  // 4096 float4 per chunk

__global__ __launch_bounds__(BLOCK) void partial_kernel(const float* __restrict__ x,
                                                        const float* __restrict__ y,
                                                        float* __restrict__ part) {
    const int blk = blockIdx.x;          // row*SPLIT + chunk
    const int row = blk / SPLIT;
    const int chunk = blk % SPLIT;
    const size_t base = (size_t)row * ROW_ELEMS + (size_t)chunk * (ROW_ELEMS / SPLIT);
    const float4* __restrict__ x4 = (const float4*)(x + base);
    const float4* __restrict__ y4 = (const float4*)(y + base);
    const int tid = threadIdx.x;

    float sx = 0.f, sy = 0.f, sxx = 0.f, syy = 0.f, sxy = 0.f;

    // CHUNK_VECS = 4096, BLOCK = 256 -> 16 float4/thread, unrolled 4x4.
    // Issue all 8 loads of a batch before any use -> 8 loads in flight/lane.
    #pragma unroll
    for (int base_i = 0; base_i < 4; ++base_i) {
        const int i = tid + base_i * (BLOCK * 4);
        float4 a0 = x4[i];
        float4 a1 = x4[i + BLOCK];
        float4 a2 = x4[i + BLOCK * 2];
        float4 a3 = x4[i + BLOCK * 3];
        float4 b0 = y4[i];
        float4 b1 = y4[i + BLOCK];
        float4 b2 = y4[i + BLOCK * 2];
        float4 b3 = y4[i + BLOCK * 3];

        sx  += (a0.x + a0.y + a0.z + a0.w) + (a1.x + a1.y + a1.z + a1.w)
             + (a2.x + a2.y + a2.z + a2.w) + (a3.x + a3.y + a3.z + a3.w);
        sy  += (b0.x + b0.y + b0.z + b0.w) + (b1.x + b1.y + b1.z + b1.w)
             + (b2.x + b2.y + b2.z + b2.w) + (b3.x + b3.y + b3.z + b3.w);
        sxx += a0.x*a0.x + a0.y*a0.y + a0.z*a0.z + a0.w*a0.w
             + a1.x*a1.x + a1.y*a1.y + a1.z*a1.z + a1.w*a1.w
             + a2.x*a2.x + a2.y*a2.y + a2.z*a2.z + a2.w*a2.w
             + a3.x*a3.x + a3.y*a3.y + a3.z*a3.z + a3.w*a3.w;
        syy += b0.x*b0.x + b0.y*b0.y + b0.z*b0.z + b0.w*b0.w
             + b1.x*b1.x + b1.y*b1.y + b1.z*b1.z + b1.w*b1.w
             + b2.x*b2.x + b2.y*b2.y + b2.z*b2.z + b2.w*b2.w
             + b3.x*b3.x + b3.y*b3.y + b3.z*b3.z + b3.w*b3.w;
        sxy += a0.x*b0.x + a0.y*b0.y + a0.z*b0.z + a0.w*b0.w
             + a1.x*b1.x + a1.y*b1.y + a1.z*b1.z + a1.w*b1.w
             + a2.x*b2.x + a2.y*b2.y + a2.z*b2.z + a2.w*b2.w
             + a3.x*b3.x + a3.y*b3.y + a3.z*b3.z + a3.w*b3.w;
    }

    // 64-lane wave shuffle reduction
    #pragma unroll
    for (int off = 32; off > 0; off >>= 1) {
        sx  += __shfl_down(sx,  off);
        sy  += __shfl_down(sy,  off);
        sxx += __shfl_down(sxx, off);
        syy += __shfl_down(syy, off);
        sxy += __shfl_down(sxy, off);
    }

    __shared__ float sm[5][BLOCK / 64];
    const int wave = tid >> 6;
    const int lane = tid & 63;
    if (lane == 0) {
        sm[0][wave] = sx;  sm[1][wave] = sy;
        sm[2][wave] = sxx; sm[3][wave] = syy;
        sm[4][wave] = sxy;
    }
    __syncthreads();

    if (tid == 0) {
        float t0 = 0.f, t1 = 0.f, t2 = 0.f, t3 = 0.f, t4 = 0.f;
        #pragma unroll
        for (int w = 0; w < BLOCK / 64; ++w) {
            t0 += sm[0][w]; t1 += sm[1][w];
            t2 += sm[2][w]; t3 += sm[3][w];
            t4 += sm[4][w];
        }
        // struct-of-arrays for coalesced reads in pass 2
        part[0 * NBLK + blk] = t0;
        part[1 * NBLK + blk] = t1;
        part[2 * NBLK + blk] = t2;
        part[3 * NBLK + blk] = t3;
        part[4 * NBLK + blk] = t4;
    }
}

__global__ __launch_bounds__(BLOCK) void finalize_kernel(const float* __restrict__ part,
                                                         float* __restrict__ out) {
    float acc = 0.f;
    for (int row = threadIdx.x; row < ROWS; row += BLOCK) {
        float tsx = 0.f, tsy = 0.f, tsxx = 0.f, tsyy = 0.f, tsxy = 0.f;
        #pragma unroll
        for (int c = 0; c < SPLIT; ++c) {
            const int b = row * SPLIT + c;
            tsx  += part[0 * NBLK + b];
            tsy  += part[1 * NBLK + b];
            tsxx += part[2 * NBLK + b];
            tsyy += part[3 * NBLK + b];
            tsxy += part[4 * NBLK + b];
        }
        const float n = (float)ROW_ELEMS;
        const float inv_nm1 = 1.0f / (n - 1.0f);
        float vx  = (tsxx - tsx * tsx / n) * inv_nm1;
        float vy  = (tsyy - tsy * tsy / n) * inv_nm1;
        float cov = (tsxy - tsx * tsy / n) * inv_nm1;
        acc += 1.0f - cov / sqrtf(fabsf(vx * vy));
    }

    #pragma unroll
    for (int off = 32; off > 0; off >>= 1) acc += __shfl_down(acc, off);

    __shared__ float sm[BLOCK / 64];
    const int wave = threadIdx.x >> 6;
    const int lane = threadIdx.x & 63;
    if (lane == 0) sm[wave] = acc;
    __syncthreads();

    if (threadIdx.x == 0) {
        float t = 0.f;
        #pragma unroll
        for (int w = 0; w < BLOCK / 64; ++w) t += sm[w];
        out[0] = t / (float)ROWS;
    }
}

extern "C" void kernel_launch(void* const* d_in, const int* in_sizes, int n_in,
                              void* d_out, int out_size, void* d_ws, size_t ws_size,
                              hipStream_t stream) {
    const float* x = (const float*)d_in[0];
    const float* y = (const float*)d_in[1];
    float* part = (float*)d_ws;   // 5 * 3072 floats = 60 KB scratch
    float* out = (float*)d_out;

    partial_kernel<<<NBLK, BLOCK, 0, stream>>>(x, y, part);
    finalize_kernel<<<1, BLOCK, 0, stream>>>(part, out);
}

// Round 3
// 358.076 us; speedup vs baseline: 1.0911x; 1.0851x over previous
//
#include <hip/hip_runtime.h>

// r = 1 - cov(x,y)/sqrt(|var(x)*var(y)|) per row (cov identity for
// 0.5*(var(x+y)-var(x)-var(y))), then mean over 768 rows.
// Pass 1: 5 sufficient stats (Sx,Sy,Sxx,Syy,Sxy) per (row,chunk) block.
// Pass 2: single block combines chunks -> per-row r -> mean.
//
// R2 lesson: VGPR_Count=32 => compiler serialized the load batch; BW pinned
// at 3.1 TB/s delivered. This version forces 16 loads in flight per thread
// (f4 arrays, full unroll, launch_bounds allowing ~128 VGPRs) + nontemporal.

#define ROWS 768          // 8*16*6
#define ROW_ELEMS 65536   // 256*256
#define BLOCK 256
#define SPLIT 4                         // chunks per row
#define NBLK (ROWS * SPLIT)             // 3072 partial blocks
#define CHUNK_VECS (ROW_ELEMS / 4 / SPLIT)  // 4096 float4 per chunk

typedef float f4 __attribute__((ext_vector_type(4)));

__global__ __launch_bounds__(BLOCK, 4) void partial_kernel(const float* __restrict__ x,
                                                           const float* __restrict__ y,
                                                           float* __restrict__ part) {
    const int blk = blockIdx.x;          // row*SPLIT + chunk
    const size_t base = (size_t)blk * (ROW_ELEMS / SPLIT);
    const f4* __restrict__ x4 = (const f4*)(x + base);
    const f4* __restrict__ y4 = (const f4*)(y + base);
    const int tid = threadIdx.x;

    f4 vsx = {0.f, 0.f, 0.f, 0.f};
    f4 vsy = {0.f, 0.f, 0.f, 0.f};
    f4 vsxx = {0.f, 0.f, 0.f, 0.f};
    f4 vsyy = {0.f, 0.f, 0.f, 0.f};
    f4 vsxy = {0.f, 0.f, 0.f, 0.f};

    // 4096 f4 per chunk / 256 threads = 16 f4/thread = 2 superbatches of
    // (8 x-f4 + 8 y-f4). All 16 loads issued before any consumption.
    #pragma unroll
    for (int it = 0; it < 2; ++it) {
        const int i = tid + it * (BLOCK * 8);
        f4 a[8], b[8];
        #pragma unroll
        for (int j = 0; j < 8; ++j)
            a[j] = __builtin_nontemporal_load(&x4[i + j * BLOCK]);
        #pragma unroll
        for (int j = 0; j < 8; ++j)
            b[j] = __builtin_nontemporal_load(&y4[i + j * BLOCK]);
        #pragma unroll
        for (int j = 0; j < 8; ++j) {
            vsx  += a[j];
            vsy  += b[j];
            vsxx += a[j] * a[j];
            vsyy += b[j] * b[j];
            vsxy += a[j] * b[j];
        }
    }

    // horizontal reduce vector accumulators to scalars
    float sx  = vsx.x  + vsx.y  + vsx.z  + vsx.w;
    float sy  = vsy.x  + vsy.y  + vsy.z  + vsy.w;
    float sxx = vsxx.x + vsxx.y + vsxx.z + vsxx.w;
    float syy = vsyy.x + vsyy.y + vsyy.z + vsyy.w;
    float sxy = vsxy.x + vsxy.y + vsxy.z + vsxy.w;

    // 64-lane wave shuffle reduction
    #pragma unroll
    for (int off = 32; off > 0; off >>= 1) {
        sx  += __shfl_down(sx,  off);
        sy  += __shfl_down(sy,  off);
        sxx += __shfl_down(sxx, off);
        syy += __shfl_down(syy, off);
        sxy += __shfl_down(sxy, off);
    }

    __shared__ float sm[5][BLOCK / 64];
    const int wave = tid >> 6;
    const int lane = tid & 63;
    if (lane == 0) {
        sm[0][wave] = sx;  sm[1][wave] = sy;
        sm[2][wave] = sxx; sm[3][wave] = syy;
        sm[4][wave] = sxy;
    }
    __syncthreads();

    if (tid == 0) {
        float t0 = 0.f, t1 = 0.f, t2 = 0.f, t3 = 0.f, t4 = 0.f;
        #pragma unroll
        for (int w = 0; w < BLOCK / 64; ++w) {
            t0 += sm[0][w]; t1 += sm[1][w];
            t2 += sm[2][w]; t3 += sm[3][w];
            t4 += sm[4][w];
        }
        // struct-of-arrays for coalesced reads in pass 2
        part[0 * NBLK + blk] = t0;
        part[1 * NBLK + blk] = t1;
        part[2 * NBLK + blk] = t2;
        part[3 * NBLK + blk] = t3;
        part[4 * NBLK + blk] = t4;
    }
}

__global__ __launch_bounds__(BLOCK) void finalize_kernel(const float* __restrict__ part,
                                                         float* __restrict__ out) {
    float acc = 0.f;
    for (int row = threadIdx.x; row < ROWS; row += BLOCK) {
        float tsx = 0.f, tsy = 0.f, tsxx = 0.f, tsyy = 0.f, tsxy = 0.f;
        #pragma unroll
        for (int c = 0; c < SPLIT; ++c) {
            const int b = row * SPLIT + c;
            tsx  += part[0 * NBLK + b];
            tsy  += part[1 * NBLK + b];
            tsxx += part[2 * NBLK + b];
            tsyy += part[3 * NBLK + b];
            tsxy += part[4 * NBLK + b];
        }
        const float n = (float)ROW_ELEMS;
        const float inv_nm1 = 1.0f / (n - 1.0f);
        float vx  = (tsxx - tsx * tsx / n) * inv_nm1;
        float vy  = (tsyy - tsy * tsy / n) * inv_nm1;
        float cov = (tsxy - tsx * tsy / n) * inv_nm1;
        acc += 1.0f - cov / sqrtf(fabsf(vx * vy));
    }

    #pragma unroll
    for (int off = 32; off > 0; off >>= 1) acc += __shfl_down(acc, off);

    __shared__ float sm[BLOCK / 64];
    const int wave = threadIdx.x >> 6;
    const int lane = threadIdx.x & 63;
    if (lane == 0) sm[wave] = acc;
    __syncthreads();

    if (threadIdx.x == 0) {
        float t = 0.f;
        #pragma unroll
        for (int w = 0; w < BLOCK / 64; ++w) t += sm[w];
        out[0] = t / (float)ROWS;
    }
}

extern "C" void kernel_launch(void* const* d_in, const int* in_sizes, int n_in,
                              void* d_out, int out_size, void* d_ws, size_t ws_size,
                              hipStream_t stream) {
    const float* x = (const float*)d_in[0];
    const float* y = (const float*)d_in[1];
    float* part = (float*)d_ws;   // 5 * 3072 floats = 60 KB scratch
    float* out = (float*)d_out;

    partial_kernel<<<NBLK, BLOCK, 0, stream>>>(x, y, part);
    finalize_kernel<<<1, BLOCK, 0, stream>>>(part, out);
}